// Round 6
// baseline (80.640 us; speedup 1.0000x reference)
//
#include <hip/hip_runtime.h>

#define N_   64
#define D_   128
#define L_   3136
#define K_   64
#define TL_  64
#define NG_  12     // pixel groups per image -> grid = 64*12 = 768 = 3 blocks/CU
// tiles per group: g==0 -> 5, else 4 (5 + 11*4 = 49 tiles of 64 pixels)
#define ASTR 68     // As row stride in floats (272B: conflict-free writes, 16B-aligned rows)

typedef short  short8  __attribute__((ext_vector_type(8)));
typedef short  short4v __attribute__((ext_vector_type(4)));
typedef float  f32x16  __attribute__((ext_vector_type(16)));

static __device__ __forceinline__ unsigned short f2bf(float f) {
    unsigned u = __float_as_uint(f);                       // RNE f32 -> bf16 bits
    return (unsigned short)((u + 0x7FFFu + ((u >> 16) & 1u)) >> 16);
}

// Full-MFMA fused NetVLAD main (r5 structure + r6 latency fixes):
//  - 3 blocks/CU (NG=12, LDS 50.0KB)
//  - register prefetch of next tile's x (issued after bar1, consumed next stage)
//  - As in fp32 (1 dword/lane stores -> no bank conflicts), unioned with red_ss
__global__ __launch_bounds__(256, 3)
void vlad_main(const float* __restrict__ x, const float* __restrict__ w,
               float* __restrict__ vout, float* __restrict__ aout,
               int vstride, int astride)   // vstride==0 => atomic accumulate path
{
    __shared__ __align__(16) short L1[TL_ * D_];   // [l][dk] bf16, swz ^((l&15)<<4), 16KB
    __shared__ __align__(16) short L2[D_ * TL_];   // [dk][l] bf16, swz ^((dk&7)<<4), 16KB
    __shared__ __align__(16) float AsU[K_ * ASTR]; // f32 a*inv [k][p]; rows 0..15 double as red_ss; 17.4KB
    __shared__ float inv_lds[TL_], nrm_lds[TL_];
    __shared__ float dred[4][32];                  // softmax denominator exchange

    const int t    = threadIdx.x;
    const int lane = t & 63;
    const int wv   = __builtin_amdgcn_readfirstlane(t >> 6);  // 0..3
    const int n    = blockIdx.x / NG_;
    const int g    = blockIdx.x % NG_;
    const int tile0 = (g == 0) ? 0 : (4 * g + 1);
    const int ntile = (g == 0) ? 5 : 4;

    const int Mt = wv & 1;     // cluster-half (M) for both phases
    const int lg = lane >> 5;  // k-element group (0/1)
    const int lm = lane & 31;

    char* L1b = (char*)L1;
    char* L2b = (char*)L2;
    float (*red_ss)[ASTR] = (float (*)[ASTR])AsU;  // union: transient, consumed before As written

    // ---- W fragments, loop-invariant, kept in 32 VGPRs ----
    short8 wf[8];
#pragma unroll
    for (int ks = 0; ks < 8; ++ks) {
        const float* wp = w + (size_t)(32 * Mt + lm) * D_ + 16 * ks + 8 * lg;
        const float4 wa = *(const float4*)wp;
        const float4 wb = *(const float4*)(wp + 4);
        short8 f;
        f[0]=f2bf(wa.x); f[1]=f2bf(wa.y); f[2]=f2bf(wa.z); f[3]=f2bf(wa.w);
        f[4]=f2bf(wb.x); f[5]=f2bf(wb.y); f[6]=f2bf(wb.z); f[7]=f2bf(wb.w);
        wf[ks] = f;
    }

    f32x16 acc0 = {0};   // V[k][d] C-frag, d-tile 2*(wv>>1)
    f32x16 acc1 = {0};   // d-tile 2*(wv>>1)+1
    float asum_acc = 0.f;

    const int q  = t >> 4;          // staging: d-rows 8q..8q+7
    const int l0 = (t & 15) * 4;    // staging: 4 pixels
    const float* xb = x + (size_t)n * D_ * L_;

    // ---- prologue: prefetch tile 0 into registers ----
    float4 v[8];
    {
        const int p0 = tile0 * TL_;
#pragma unroll
        for (int r = 0; r < 8; ++r)
            v[r] = *(const float4*)(xb + (size_t)(8 * q + r) * L_ + p0 + l0);
    }

    for (int ti = 0; ti < ntile; ++ti) {
        __syncthreads();  // bar0: prior tile's L2/As consumers done
        // ---- stage from registers: sumsq + bf16 convert + L1 + L2 ----
#pragma unroll
        for (int j = 0; j < 4; ++j) {
            float s = 0.f;
#pragma unroll
            for (int r = 0; r < 8; ++r) {
                const float val = (&v[r].x)[j];
                s = fmaf(val, val, s);
            }
            red_ss[q][l0 + j] = s;
        }
        unsigned short sh[8][4];
#pragma unroll
        for (int r = 0; r < 8; ++r)
#pragma unroll
            for (int j = 0; j < 4; ++j) sh[r][j] = f2bf((&v[r].x)[j]);
#pragma unroll
        for (int j = 0; j < 4; ++j) {   // L1: per pixel, 8 consecutive dk (b128)
            const int l = l0 + j;
            short8 f;
#pragma unroll
            for (int r = 0; r < 8; ++r) f[r] = sh[r][j];
            *(short8*)(L1b + l * 256 + ((16 * q) ^ ((l & 15) << 4))) = f;
        }
#pragma unroll
        for (int r = 0; r < 8; ++r) {   // L2: per d, 4 consecutive l (b64)
            const int d = 8 * q + r;
            short4v f;
#pragma unroll
            for (int j = 0; j < 4; ++j) f[j] = sh[r][j];
            *(short4v*)(L2b + d * 128 + ((l0 * 2) ^ ((d & 7) << 4))) = f;
        }
        __syncthreads();  // bar1: tile staged; red_ss complete
        // ---- prefetch next tile (latency hidden under phase1+softmax+phase2) ----
        if (ti + 1 < ntile) {
            const int p0n = (tile0 + ti + 1) * TL_;
#pragma unroll
            for (int r = 0; r < 8; ++r)
                v[r] = *(const float4*)(xb + (size_t)(8 * q + r) * L_ + p0n + l0);
        }
        if (t < TL_) {
            float ss = 0.f;
#pragma unroll
            for (int qq = 0; qq < 16; ++qq) ss += red_ss[qq][t];
            const float nr = fmaxf(sqrtf(ss), 1e-12f);
            nrm_lds[t] = nr;
            inv_lds[t] = 1.f / nr;
        }
        // ---- phase 1: R = W * X (quadrant Mt x Nt), contraction dk=128 ----
        f32x16 r1 = {0};
        {
            const int l = 32 * (wv >> 1) + lm;   // pixel = col = lane&31
            const int rowoff = l * 256;
            const int swz = (l & 15) << 4;
#pragma unroll
            for (int ks = 0; ks < 8; ++ks) {
                const short8 bfr = *(short8*)(L1b + rowoff + (((16 * ks + 8 * lg) * 2) ^ swz));
                r1 = __builtin_amdgcn_mfma_f32_32x32x16_bf16(wf[ks], bfr, r1, 0, 0, 0);
            }
        }
        __syncthreads();  // bar2: inv/nrm visible to all
        // ---- softmax over k (no max-sub; |logit*inv| <= ||w_k|| ~ 0.6) ----
        const float invp = inv_lds[32 * (wv >> 1) + lm];
        float e[16];
        float s = 0.f;
#pragma unroll
        for (int r = 0; r < 16; ++r) { e[r] = __expf(r1[r] * invp); s += e[r]; }
        s += __shfl_xor(s, 32);              // combine the two k-halves per pixel
        if (lane < 32) dred[wv][lm] = s;
        __syncthreads();  // bar3
        const float denom = dred[wv][lm] + dred[wv ^ 1][lm];   // cross-Mt partner
        const float sc = invp / denom;       // A_s = a * inv (agg uses raw X)
#pragma unroll
        for (int r = 0; r < 16; ++r) {       // f32 store: 1 dword/lane, conflict-free
            const int k = 32 * Mt + (r & 3) + 8 * (r >> 2) + 4 * lg;
            AsU[k * ASTR + 32 * (wv >> 1) + lm] = e[r] * sc;
        }
        __syncthreads();  // bar4: A_s ready
        // ---- phase 2: V += A_s * X^T, contraction l=64 ----
        {
            short8 af[4];
            const float* arow = AsU + (32 * Mt + lm) * ASTR;
#pragma unroll
            for (int ks = 0; ks < 4; ++ks) {
                const float* ap = arow + 16 * ks + 8 * lg;
                const float4 a0 = *(const float4*)ap;
                const float4 a1 = *(const float4*)(ap + 4);
                short8 f;
                f[0]=f2bf(a0.x); f[1]=f2bf(a0.y); f[2]=f2bf(a0.z); f[3]=f2bf(a0.w);
                f[4]=f2bf(a1.x); f[5]=f2bf(a1.y); f[6]=f2bf(a1.z); f[7]=f2bf(a1.w);
                af[ks] = f;
            }
#pragma unroll
            for (int nt = 0; nt < 2; ++nt) {
                const int dk = 32 * (2 * (wv >> 1) + nt) + lm;  // d = col = lane&31
                const int rowoff = dk * 128;
                const int swz = (dk & 7) << 4;
                f32x16 a = (nt == 0) ? acc0 : acc1;
#pragma unroll
                for (int ks = 0; ks < 4; ++ks) {
                    const short8 bfr = *(short8*)(L2b + rowoff + (((16 * ks + 8 * lg) * 2) ^ swz));
                    a = __builtin_amdgcn_mfma_f32_32x32x16_bf16(af[ks], bfr, a, 0, 0, 0);
                }
                if (nt == 0) acc0 = a; else acc1 = a;
            }
        }
        // ---- asum partial: asum[k] += sum_l A_s[k][l]*nrm[l] (f32 reads) ----
        {
            const int k  = 16 * wv + (lane & 15);
            const int c4 = lane >> 4;                 // l-chunk 16*c4
            const float* ap = AsU + k * ASTR + 16 * c4;
            float ps = 0.f;
#pragma unroll
            for (int i = 0; i < 16; ++i)
                ps = fmaf(ap[i], nrm_lds[16 * c4 + i], ps);
            ps += __shfl_xor(ps, 16);
            ps += __shfl_xor(ps, 32);
            asum_acc += ps;
        }
    }
    // ---- commit: per-group slab (plain stores) or atomic fallback ----
    {
        const int dbase0 = 32 * (2 * (wv >> 1));
        float* vb = vstride ? (vout + (size_t)g * vstride) : vout;
#pragma unroll
        for (int r = 0; r < 16; ++r) {
            const int k = 32 * Mt + (r & 3) + 8 * (r >> 2) + 4 * lg;
            float* row = vb + ((size_t)n * K_ + k) * D_ + lm;
            if (vstride) {
                row[dbase0]      = acc0[r];
                row[dbase0 + 32] = acc1[r];
            } else {
                atomicAdd(&row[dbase0],      acc0[r]);
                atomicAdd(&row[dbase0 + 32], acc1[r]);
            }
        }
        if (lane < 16) {
            const int k = 16 * wv + lane;
            if (astride) aout[(size_t)g * astride + n * K_ + k] = asum_acc;
            else atomicAdd(&aout[n * K_ + k], asum_acc);
        }
    }
}

// Finalize: sum partials; v = V - asum*c; intra-norm over d; global norm.
__global__ __launch_bounds__(256)
void vlad_fin(const float* __restrict__ vacc, const float* __restrict__ asum,
              const float* __restrict__ cent, float* __restrict__ out, int npart)
{
    __shared__ float sred[4];
    const int t = threadIdx.x;
    const int n = blockIdx.x;
    const int k = t >> 2;
    const int qq = t & 3;

    float a = 0.f;
    for (int g = 0; g < npart; ++g) a += asum[(size_t)g * (N_ * K_) + n * K_ + k];

    const float* cc = cent + (size_t)k * D_ + qq * 32;
    const size_t off = ((size_t)n * K_ + k) * D_ + qq * 32;
    float v[32];
#pragma unroll
    for (int j = 0; j < 32; ++j) v[j] = 0.f;
    for (int g = 0; g < npart; ++g) {
        const float* src = vacc + (size_t)g * ((size_t)N_ * K_ * D_) + off;
#pragma unroll
        for (int j = 0; j < 32; ++j) v[j] += src[j];
    }
    float ss = 0.f;
#pragma unroll
    for (int j = 0; j < 32; ++j) {
        v[j] = v[j] - a * cc[j];
        ss = fmaf(v[j], v[j], ss);
    }
    ss += __shfl_xor(ss, 1);
    ss += __shfl_xor(ss, 2);
    const float inv1 = 1.f / fmaxf(sqrtf(ss), 1e-12f);
    float gs = 0.f;
#pragma unroll
    for (int j = 0; j < 32; ++j) { v[j] *= inv1; gs = fmaf(v[j], v[j], gs); }
#pragma unroll
    for (int off2 = 1; off2 < 64; off2 <<= 1) gs += __shfl_xor(gs, off2);
    const int wv = t >> 6;
    if ((t & 63) == 0) sred[wv] = gs;
    __syncthreads();
    const float tot = sred[0] + sred[1] + sred[2] + sred[3];
    const float inv2 = 1.f / fmaxf(sqrtf(tot), 1e-12f);
    float* dst = out + (size_t)n * (K_ * D_) + (size_t)k * D_ + qq * 32;
#pragma unroll
    for (int j = 0; j < 32; ++j) dst[j] = v[j] * inv2;
}

extern "C" void kernel_launch(void* const* d_in, const int* in_sizes, int n_in,
                              void* d_out, int out_size, void* d_ws, size_t ws_size,
                              hipStream_t stream)
{
    const float* x = (const float*)d_in[0];   // [N, D, H, W]
    const float* w = (const float*)d_in[1];   // [K, D]
    const float* c = (const float*)d_in[2];   // [K, D]
    float* out = (float*)d_out;               // [N, K*D]

    const size_t vs  = (size_t)N_ * K_ * D_;  // 524288
    const size_t as_ = (size_t)N_ * K_;       // 4096
    const size_t need = (NG_ * vs + NG_ * as_) * sizeof(float);  // ~25.4 MB
    float* vacc = (float*)d_ws;

    if (ws_size >= need) {
        float* ap = vacc + NG_ * vs;
        vlad_main<<<dim3(N_ * NG_), dim3(256), 0, stream>>>(x, w, vacc, ap,
                                                            (int)vs, (int)as_);
        vlad_fin<<<dim3(N_), dim3(256), 0, stream>>>(vacc, ap, c, out, NG_);
    } else {
        float* ap = vacc + vs;
        hipMemsetAsync(d_ws, 0, (vs + as_) * sizeof(float), stream);
        vlad_main<<<dim3(N_ * NG_), dim3(256), 0, stream>>>(x, w, vacc, ap, 0, 0);
        vlad_fin<<<dim3(N_), dim3(256), 0, stream>>>(vacc, ap, c, out, 1);
    }
}

// Round 7
// 53.198 us; speedup vs baseline: 1.5158x; 1.5158x over previous
//
#include <hip/hip_runtime.h>

#define N_   64
#define D_   128
#define L_   3136
#define K_   64
#define TL_  64
#define NG_  12     // pixel groups per image -> grid = 64*12 = 768 = 3 blocks/CU
// tiles per group: g==0 -> 5, else 4 (5 + 11*4 = 49 tiles of 64 pixels)
#define ASTR 68     // As row stride in floats (272B: conflict-free f32 col writes)

typedef short  short8  __attribute__((ext_vector_type(8)));
typedef short  short4v __attribute__((ext_vector_type(4)));
typedef float  f32x16  __attribute__((ext_vector_type(16)));

static __device__ __forceinline__ unsigned short f2bf(float f) {
    unsigned u = __float_as_uint(f);                       // RNE f32 -> bf16 bits
    return (unsigned short)((u + 0x7FFFu + ((u >> 16) & 1u)) >> 16);
}

// Full-MFMA fused NetVLAD main (r5 structure + NG=12 occupancy + fp32 As).
// r6 lesson: register prefetch across __syncthreads spills (compiler pins VGPR
// at 84) AND is drained by the compiler's vmcnt(0)-before-s_barrier one phase
// later -- removed. Loads are issued at iteration top, consumed immediately;
// cross-block TLP (3 blocks/CU) covers the staging stream.
__global__ __launch_bounds__(256, 3)
void vlad_main(const float* __restrict__ x, const float* __restrict__ w,
               float* __restrict__ vout, float* __restrict__ aout,
               int vstride, int astride)   // vstride==0 => atomic accumulate path
{
    __shared__ __align__(16) short L1[TL_ * D_];   // [l][dk] bf16, swz ^((l&15)<<4), 16KB
    __shared__ __align__(16) short L2[D_ * TL_];   // [dk][l] bf16, swz ^((dk&7)<<4), 16KB
    __shared__ __align__(16) float AsU[K_ * ASTR]; // f32 a*inv [k][p]; rows 0..15 double as red_ss; 17.4KB
    __shared__ float inv_lds[TL_], nrm_lds[TL_];
    __shared__ float dred[4][32];                  // softmax denominator exchange

    const int t    = threadIdx.x;
    const int lane = t & 63;
    const int wv   = __builtin_amdgcn_readfirstlane(t >> 6);  // 0..3
    const int n    = blockIdx.x / NG_;
    const int g    = blockIdx.x % NG_;
    const int tile0 = (g == 0) ? 0 : (4 * g + 1);
    const int ntile = (g == 0) ? 5 : 4;

    const int Mt = wv & 1;     // cluster-half (M) for both phases
    const int lg = lane >> 5;  // k-element group (0/1)
    const int lm = lane & 31;

    char* L1b = (char*)L1;
    char* L2b = (char*)L2;
    float (*red_ss)[ASTR] = (float (*)[ASTR])AsU;  // union: consumed before As written

    // ---- W fragments, loop-invariant, kept in 32 VGPRs ----
    short8 wf[8];
#pragma unroll
    for (int ks = 0; ks < 8; ++ks) {
        const float* wp = w + (size_t)(32 * Mt + lm) * D_ + 16 * ks + 8 * lg;
        const float4 wa = *(const float4*)wp;
        const float4 wb = *(const float4*)(wp + 4);
        short8 f;
        f[0]=f2bf(wa.x); f[1]=f2bf(wa.y); f[2]=f2bf(wa.z); f[3]=f2bf(wa.w);
        f[4]=f2bf(wb.x); f[5]=f2bf(wb.y); f[6]=f2bf(wb.z); f[7]=f2bf(wb.w);
        wf[ks] = f;
    }

    f32x16 acc0 = {0};   // V[k][d] C-frag, d-tile 2*(wv>>1)
    f32x16 acc1 = {0};   // d-tile 2*(wv>>1)+1
    float asum_acc = 0.f;

    const int q  = t >> 4;          // staging: d-rows 8q..8q+7
    const int l0 = (t & 15) * 4;    // staging: 4 pixels
    const float* xb = x + (size_t)n * D_ * L_;

    for (int ti = 0; ti < ntile; ++ti) {
        const int p0 = (tile0 + ti) * TL_;
        __syncthreads();  // bar0: prior tile's L2/As consumers done
        // ---- stage: 8 float4 (8 d x 4 l) -> sumsq + bf16 + L1 + L2 ----
        float4 v[8];
#pragma unroll
        for (int r = 0; r < 8; ++r)
            v[r] = *(const float4*)(xb + (size_t)(8 * q + r) * L_ + p0 + l0);
#pragma unroll
        for (int j = 0; j < 4; ++j) {
            float s = 0.f;
#pragma unroll
            for (int r = 0; r < 8; ++r) {
                const float val = (&v[r].x)[j];
                s = fmaf(val, val, s);
            }
            red_ss[q][l0 + j] = s;
        }
        unsigned short sh[8][4];
#pragma unroll
        for (int r = 0; r < 8; ++r)
#pragma unroll
            for (int j = 0; j < 4; ++j) sh[r][j] = f2bf((&v[r].x)[j]);
#pragma unroll
        for (int j = 0; j < 4; ++j) {   // L1: per pixel, 8 consecutive dk (b128)
            const int l = l0 + j;
            short8 f;
#pragma unroll
            for (int r = 0; r < 8; ++r) f[r] = sh[r][j];
            *(short8*)(L1b + l * 256 + ((16 * q) ^ ((l & 15) << 4))) = f;
        }
#pragma unroll
        for (int r = 0; r < 8; ++r) {   // L2: per d, 4 consecutive l (b64)
            const int d = 8 * q + r;
            short4v f;
#pragma unroll
            for (int j = 0; j < 4; ++j) f[j] = sh[r][j];
            *(short4v*)(L2b + d * 128 + ((l0 * 2) ^ ((d & 7) << 4))) = f;
        }
        __syncthreads();  // bar1: tile staged; red_ss complete
        if (t < TL_) {
            float ss = 0.f;
#pragma unroll
            for (int qq = 0; qq < 16; ++qq) ss += red_ss[qq][t];
            const float nr = fmaxf(sqrtf(ss), 1e-12f);
            nrm_lds[t] = nr;
            inv_lds[t] = 1.f / nr;
        }
        // ---- phase 1: R = W * X (quadrant Mt x Nt), contraction dk=128 ----
        f32x16 r1 = {0};
        {
            const int l = 32 * (wv >> 1) + lm;   // pixel = col = lane&31
            const int rowoff = l * 256;
            const int swz = (l & 15) << 4;
#pragma unroll
            for (int ks = 0; ks < 8; ++ks) {
                const short8 bfr = *(short8*)(L1b + rowoff + (((16 * ks + 8 * lg) * 2) ^ swz));
                r1 = __builtin_amdgcn_mfma_f32_32x32x16_bf16(wf[ks], bfr, r1, 0, 0, 0);
            }
        }
        __syncthreads();  // bar2: inv/nrm visible to all
        // ---- softmax over k (no max-sub; |logit*inv| <= ||w_k|| ~ 0.6) ----
        const float invp = inv_lds[32 * (wv >> 1) + lm];
        float e[16];
        float s = 0.f;
#pragma unroll
        for (int r = 0; r < 16; ++r) { e[r] = __expf(r1[r] * invp); s += e[r]; }
        s += __shfl_xor(s, 32);              // combine the two k-halves per pixel
        if (lane < 32) dred[wv][lm] = s;
        __syncthreads();  // bar3
        const float denom = dred[wv][lm] + dred[wv ^ 1][lm];   // cross-Mt partner
        const float sc = invp / denom;       // A_s = a * inv (agg uses raw X)
#pragma unroll
        for (int r = 0; r < 16; ++r) {       // f32 store: 1 dword/lane, conflict-free
            const int k = 32 * Mt + (r & 3) + 8 * (r >> 2) + 4 * lg;
            AsU[k * ASTR + 32 * (wv >> 1) + lm] = e[r] * sc;
        }
        __syncthreads();  // bar4: A_s ready
        // ---- phase 2: V += A_s * X^T, contraction l=64 ----
        {
            short8 af[4];
            const float* arow = AsU + (32 * Mt + lm) * ASTR;
#pragma unroll
            for (int ks = 0; ks < 4; ++ks) {
                const float* ap = arow + 16 * ks + 8 * lg;
                const float4 a0 = *(const float4*)ap;
                const float4 a1 = *(const float4*)(ap + 4);
                short8 f;
                f[0]=f2bf(a0.x); f[1]=f2bf(a0.y); f[2]=f2bf(a0.z); f[3]=f2bf(a0.w);
                f[4]=f2bf(a1.x); f[5]=f2bf(a1.y); f[6]=f2bf(a1.z); f[7]=f2bf(a1.w);
                af[ks] = f;
            }
#pragma unroll
            for (int nt = 0; nt < 2; ++nt) {
                const int dk = 32 * (2 * (wv >> 1) + nt) + lm;  // d = col = lane&31
                const int rowoff = dk * 128;
                const int swz = (dk & 7) << 4;
                f32x16 a = (nt == 0) ? acc0 : acc1;
#pragma unroll
                for (int ks = 0; ks < 4; ++ks) {
                    const short8 bfr = *(short8*)(L2b + rowoff + (((16 * ks + 8 * lg) * 2) ^ swz));
                    a = __builtin_amdgcn_mfma_f32_32x32x16_bf16(af[ks], bfr, a, 0, 0, 0);
                }
                if (nt == 0) acc0 = a; else acc1 = a;
            }
        }
        // ---- asum partial: asum[k] += sum_l A_s[k][l]*nrm[l] (f32 reads) ----
        {
            const int k  = 16 * wv + (lane & 15);
            const int c4 = lane >> 4;                 // l-chunk 16*c4
            const float* ap = AsU + k * ASTR + 16 * c4;
            float ps = 0.f;
#pragma unroll
            for (int i = 0; i < 16; ++i)
                ps = fmaf(ap[i], nrm_lds[16 * c4 + i], ps);
            ps += __shfl_xor(ps, 16);
            ps += __shfl_xor(ps, 32);
            asum_acc += ps;
        }
    }
    // ---- commit: per-group slab (plain stores) or atomic fallback ----
    {
        const int dbase0 = 32 * (2 * (wv >> 1));
        float* vb = vstride ? (vout + (size_t)g * vstride) : vout;
#pragma unroll
        for (int r = 0; r < 16; ++r) {
            const int k = 32 * Mt + (r & 3) + 8 * (r >> 2) + 4 * lg;
            float* row = vb + ((size_t)n * K_ + k) * D_ + lm;
            if (vstride) {
                row[dbase0]      = acc0[r];
                row[dbase0 + 32] = acc1[r];
            } else {
                atomicAdd(&row[dbase0],      acc0[r]);
                atomicAdd(&row[dbase0 + 32], acc1[r]);
            }
        }
        if (lane < 16) {
            const int k = 16 * wv + lane;
            if (astride) aout[(size_t)g * astride + n * K_ + k] = asum_acc;
            else atomicAdd(&aout[n * K_ + k], asum_acc);
        }
    }
}

// Finalize: sum partials (float4 loads); v = V - asum*c; intra-norm; global norm.
__global__ __launch_bounds__(256)
void vlad_fin(const float* __restrict__ vacc, const float* __restrict__ asum,
              const float* __restrict__ cent, float* __restrict__ out, int npart)
{
    __shared__ float sred[4];
    const int t = threadIdx.x;
    const int n = blockIdx.x;
    const int k = t >> 2;
    const int qq = t & 3;

    float a = 0.f;
    for (int g = 0; g < npart; ++g) a += asum[(size_t)g * (N_ * K_) + n * K_ + k];

    const float4* cc4 = (const float4*)(cent + (size_t)k * D_ + qq * 32);
    const size_t off4 = (((size_t)n * K_ + k) * D_ + qq * 32) >> 2;
    float4 v4[8];
#pragma unroll
    for (int j = 0; j < 8; ++j) v4[j] = make_float4(0.f, 0.f, 0.f, 0.f);
    for (int g = 0; g < npart; ++g) {
        const float4* src4 = (const float4*)(vacc + (size_t)g * ((size_t)N_ * K_ * D_)) + off4;
#pragma unroll
        for (int j = 0; j < 8; ++j) {
            const float4 s4 = src4[j];
            v4[j].x += s4.x; v4[j].y += s4.y; v4[j].z += s4.z; v4[j].w += s4.w;
        }
    }
    float ss = 0.f;
#pragma unroll
    for (int j = 0; j < 8; ++j) {
        const float4 c4 = cc4[j];
        v4[j].x -= a * c4.x; v4[j].y -= a * c4.y;
        v4[j].z -= a * c4.z; v4[j].w -= a * c4.w;
        ss = fmaf(v4[j].x, v4[j].x, ss); ss = fmaf(v4[j].y, v4[j].y, ss);
        ss = fmaf(v4[j].z, v4[j].z, ss); ss = fmaf(v4[j].w, v4[j].w, ss);
    }
    ss += __shfl_xor(ss, 1);
    ss += __shfl_xor(ss, 2);
    const float inv1 = 1.f / fmaxf(sqrtf(ss), 1e-12f);
    float gs = 0.f;
#pragma unroll
    for (int j = 0; j < 8; ++j) {
        v4[j].x *= inv1; v4[j].y *= inv1; v4[j].z *= inv1; v4[j].w *= inv1;
        gs = fmaf(v4[j].x, v4[j].x, gs); gs = fmaf(v4[j].y, v4[j].y, gs);
        gs = fmaf(v4[j].z, v4[j].z, gs); gs = fmaf(v4[j].w, v4[j].w, gs);
    }
#pragma unroll
    for (int off2 = 1; off2 < 64; off2 <<= 1) gs += __shfl_xor(gs, off2);
    const int wv = t >> 6;
    if ((t & 63) == 0) sred[wv] = gs;
    __syncthreads();
    const float tot = sred[0] + sred[1] + sred[2] + sred[3];
    const float inv2 = 1.f / fmaxf(sqrtf(tot), 1e-12f);
    float4* dst4 = (float4*)(out + (size_t)n * (K_ * D_) + (size_t)k * D_ + qq * 32);
#pragma unroll
    for (int j = 0; j < 8; ++j) {
        float4 o = v4[j];
        o.x *= inv2; o.y *= inv2; o.z *= inv2; o.w *= inv2;
        dst4[j] = o;
    }
}

extern "C" void kernel_launch(void* const* d_in, const int* in_sizes, int n_in,
                              void* d_out, int out_size, void* d_ws, size_t ws_size,
                              hipStream_t stream)
{
    const float* x = (const float*)d_in[0];   // [N, D, H, W]
    const float* w = (const float*)d_in[1];   // [K, D]
    const float* c = (const float*)d_in[2];   // [K, D]
    float* out = (float*)d_out;               // [N, K*D]

    const size_t vs  = (size_t)N_ * K_ * D_;  // 524288
    const size_t as_ = (size_t)N_ * K_;       // 4096
    const size_t need = (NG_ * vs + NG_ * as_) * sizeof(float);  // ~25.4 MB
    float* vacc = (float*)d_ws;

    if (ws_size >= need) {
        float* ap = vacc + NG_ * vs;
        vlad_main<<<dim3(N_ * NG_), dim3(256), 0, stream>>>(x, w, vacc, ap,
                                                            (int)vs, (int)as_);
        vlad_fin<<<dim3(N_), dim3(256), 0, stream>>>(vacc, ap, c, out, NG_);
    } else {
        float* ap = vacc + vs;
        hipMemsetAsync(d_ws, 0, (vs + as_) * sizeof(float), stream);
        vlad_main<<<dim3(N_ * NG_), dim3(256), 0, stream>>>(x, w, vacc, ap, 0, 0);
        vlad_fin<<<dim3(N_), dim3(256), 0, stream>>>(vacc, ap, c, out, 1);
    }
}